// Round 8
// baseline (78.705 us; speedup 1.0000x reference)
//
#include <hip/hip_runtime.h>
#include <hip/hip_bf16.h>

// MMD loss, MI355X. Round 7: LDS-staged int8 Gram (global_load_lds dedupe,
// m97 2-barrier double-buffer), craw (bandwidth) fused into kmain.
//
// ws layout (NEED = 327680 + 4 MiB):
//   [0,32768)          float sq[8192]     raw sum q^2 per row (integer-exact)
//   [32768,34816)      float v[512]       col sums of q (integer-exact)
//   [295040,303360)    float Fpart[2080]
//   [327680,+4 MiB)    int8 img: 64 panels x 8 kp x 8 groups x 64 lanes x 16B
//     lane chunk = rows g*16+(lane&15), cols kp*64 + (lane>>4)*16 .. +16

typedef int   i32x4 __attribute__((ext_vector_type(4)));

#define N_TOT  8192
#define NHALF  4096
#define DIM    512
#define BM     128
#define TILES  64
#define NPAIRS 2080
#define QSCALE 24.0f
#define IMG_OFF    327680ULL

__device__ __forceinline__ int q8(float x) {
    int q = __float2int_rn(x * QSCALE);
    return max(-127, min(127, q));
}

__device__ __forceinline__ void gload16(const void* g, void* l) {
    __builtin_amdgcn_global_load_lds(
        (const __attribute__((address_space(1))) unsigned int*)g,
        (__attribute__((address_space(3))) unsigned int*)l, 16, 0, 0);
}

// pre-pass: 512 blocks = (panel p, kp). 128 rows x 64 cols each.
// Emits fragment-major i8 image; integer-exact row-sq and col-sum atomics.
__global__ __launch_bounds__(256) void k_pre(
    const float* __restrict__ src, const float* __restrict__ tgt,
    unsigned char* __restrict__ img,
    float* __restrict__ sq, float* __restrict__ v)
{
    __shared__ __align__(16) signed char qt[BM][80];
    const int b = blockIdx.x;
    const int p = b >> 3, kp = b & 7;
    const int t = threadIdx.x;
    const float* base = ((p < 32) ? src + (size_t)p * BM * DIM
                                  : tgt + (size_t)(p - 32) * BM * DIM) + kp * 64;

    {
        int r = t >> 1, ch = (t & 1) * 32;
        const float* qp = base + (size_t)r * DIM + ch;
        float rsq = 0.f;
        #pragma unroll
        for (int j = 0; j < 8; ++j) {
            float4 x = *(const float4*)(qp + j * 4);
            int q0 = q8(x.x), q1 = q8(x.y), q2 = q8(x.z), q3 = q8(x.w);
            unsigned int w = (q0 & 255) | ((q1 & 255) << 8) | ((q2 & 255) << 16)
                             | ((unsigned)(q3 & 255) << 24);
            *(unsigned int*)&qt[r][ch + j * 4] = w;
            rsq += (float)(q0 * q0 + q1 * q1 + q2 * q2 + q3 * q3);
        }
        rsq += __shfl_xor(rsq, 1);
        if ((t & 1) == 0) atomicAdd(&sq[p * BM + r], rsq);
    }
    __syncthreads();
    #pragma unroll
    for (int h = 0; h < 2; ++h) {
        int ci = t + h * 256;                 // 0..511 = g*64 + lane
        int g = ci >> 6, lane = ci & 63;
        int row = g * 16 + (lane & 15), c0 = (lane >> 4) * 16;
        uint4 w = *(const uint4*)&qt[row][c0];
        *(uint4*)(img + (size_t)p * 65536 + (size_t)kp * 8192
                  + (size_t)g * 1024 + (size_t)lane * 16) = w;
    }
    if (t < 64) {
        float s = 0.f;
        for (int r = 0; r < BM; ++r) s += (float)qt[r][t];
        atomicAdd(&v[kp * 64 + t], s);
    }
}

#define MFMA16(A, B)                                                           \
    do {                                                                       \
        _Pragma("unroll")                                                      \
        for (int m_ = 0; m_ < 4; ++m_)                                         \
            _Pragma("unroll")                                                  \
            for (int n_ = 0; n_ < 4; ++n_)                                     \
                acc[m_][n_] = __builtin_amdgcn_mfma_i32_16x16x64_i8(           \
                    A[m_], B[n_], acc[m_][n_], 0, 0, 0);                       \
    } while (0)

// stage unique 16 KB (A 8KB + B 8KB) for K-step KS into lds[BUF]
#define STAGE(BUF, KS)                                                         \
    do {                                                                       \
        gload16(gA + (KS) * 8192 + gofs,        &lds[BUF][0]     + wofs);      \
        gload16(gA + (KS) * 8192 + gofs + 4096, &lds[BUF][4096]  + wofs);      \
        gload16(gB + (KS) * 8192 + gofs,        &lds[BUF][8192]  + wofs);      \
        gload16(gB + (KS) * 8192 + gofs + 4096, &lds[BUF][12288] + wofs);      \
    } while (0)

__global__ __launch_bounds__(256) void kmain(
    const unsigned char* __restrict__ img,
    const float* __restrict__ sq, const float* __restrict__ v,
    float* __restrict__ Fpart)
{
    __shared__ __align__(16) char lds[2][16384];
    __shared__ float red[4], redS[4], redV[4];

    // XCD swizzle (2080 = 8*260), then 4x4-supertile triangle walk
    int b = blockIdx.x;
    int s = (b & 7) * (NPAIRS / 8) + (b >> 3);
    int SI = 0, rem = s;
    while (rem >= 10 + 16 * (15 - SI)) { rem -= 10 + 16 * (15 - SI); ++SI; }
    int I, J;
    if (rem < 10) {
        int di = 0;
        while (rem >= 4 - di) { rem -= 4 - di; ++di; }
        I = SI * 4 + di; J = SI * 4 + di + rem;
    } else {
        rem -= 10;
        int SJ = SI + 1 + (rem >> 4);
        I = SI * 4 + ((rem >> 2) & 3);
        J = SJ * 4 + (rem & 3);
    }

    const int tid  = threadIdx.x;
    const int lane = tid & 63;
    const int wid  = tid >> 6;
    const int wr   = wid >> 1, wc = wid & 1;
    const int lhi  = lane >> 4, llo = lane & 15;

    const char* gA = (const char*)img + (size_t)I * 65536;
    const char* gB = (const char*)img + (size_t)J * 65536;
    const unsigned wofs = (unsigned)wid * 1024;   // wave-uniform LDS chunk
    const unsigned gofs = (unsigned)tid * 16;     // per-lane global offset

    // ---- bandwidth partials (identical deterministic reduction per block) ----
    float Sp = 0.f;
    #pragma unroll
    for (int i = 0; i < 32; ++i) Sp += sq[tid + i * 256];
    float Vp;
    { float v0 = v[tid], v1 = v[tid + 256]; Vp = v0 * v0 + v1 * v1; }

    // hoisted epilogue sq rows
    const int rI = I * BM, rJ = J * BM;
    float sqr_[4][4], sqc_[4];
    #pragma unroll
    for (int m = 0; m < 4; ++m)
        #pragma unroll
        for (int r = 0; r < 4; ++r)
            sqr_[m][r] = sq[rI + wr * 64 + m * 16 + lhi * 4 + r];
    #pragma unroll
    for (int n = 0; n < 4; ++n)
        sqc_[n] = sq[rJ + wc * 64 + n * 16 + llo];

    i32x4 acc[4][4];
    #pragma unroll
    for (int m = 0; m < 4; ++m)
        #pragma unroll
        for (int n = 0; n < 4; ++n) acc[m][n] = (i32x4){0, 0, 0, 0};

    // ---- K-loop: double-buffered LDS, 1 barrier per K-step ----
    STAGE(0, 0);
    __syncthreads();
    #pragma unroll
    for (int t = 0; t < 8; ++t) {
        if (t < 7) STAGE((t + 1) & 1, t + 1);
        const char* lA = &lds[t & 1][0];
        const char* lB = &lds[t & 1][8192];
        i32x4 aF[4], bF[4];
        #pragma unroll
        for (int m = 0; m < 4; ++m) {
            aF[m] = *(const i32x4*)(lA + wr * 4096 + m * 1024 + lane * 16);
            bF[m] = *(const i32x4*)(lB + wc * 4096 + m * 1024 + lane * 16);
        }
        MFMA16(aF, bF);
        __syncthreads();   // drains vmcnt (next stage done) + all reads of cur done
    }

    // ---- finish bandwidth: identical in every block ----
    #pragma unroll
    for (int off = 32; off > 0; off >>= 1) {
        Sp += __shfl_down(Sp, off);
        Vp += __shfl_down(Vp, off);
    }
    if (lane == 0) { redS[wid] = Sp; redV[wid] = Vp; }
    __syncthreads();
    float S = redS[0] + redS[1] + redS[2] + redS[3];
    float V = redV[0] + redV[1] + redV[2] + redV[3];
    float sumd2 = 2.f * (float)N_TOT * S - 2.f * V;
    float bw = sumd2 / ((float)N_TOT * (float)N_TOT - (float)N_TOT) * 0.25f;
    const float c = 1.4426950408889634f / (16.f * bw);

    float local = 0.f;
    #pragma unroll
    for (int m = 0; m < 4; ++m)
        #pragma unroll
        for (int n = 0; n < 4; ++n)
            #pragma unroll
            for (int r = 0; r < 4; ++r) {
                float d2 = sqr_[m][r] + sqc_[n] - 2.f * (float)acc[m][n][r];
                d2 = fmaxf(d2, 0.f);
                float u = __builtin_amdgcn_exp2f(-d2 * c);
                float u2 = u * u, u4 = u2 * u2, u8 = u4 * u4, u16 = u8 * u8;
                local += u + u2 + u4 + u8 + u16;
            }

    float wgt = ((I < 32) == (J < 32)) ? 1.f : -1.f;
    if (I != J) wgt *= 2.f;
    local *= wgt;

    #pragma unroll
    for (int off = 32; off > 0; off >>= 1) local += __shfl_down(local, off);
    if (lane == 0) red[wid] = local;
    __syncthreads();
    if (tid == 0) Fpart[b] = red[0] + red[1] + red[2] + red[3];
}

__global__ void k4_out(const float* __restrict__ Fpart, float* __restrict__ out) {
    int t = threadIdx.x;
    double s = 0.0;
    for (int i = t; i < NPAIRS; i += 256) s += (double)Fpart[i];
    #pragma unroll
    for (int off = 32; off > 0; off >>= 1) s += __shfl_down(s, off);
    __shared__ double r[4];
    if ((t & 63) == 0) r[t >> 6] = s;
    __syncthreads();
    if (t == 0) out[0] = (float)((r[0] + r[1] + r[2] + r[3]) / ((double)NHALF * (double)NHALF));
}

extern "C" void kernel_launch(void* const* d_in, const int* in_sizes, int n_in,
                              void* d_out, int out_size, void* d_ws, size_t ws_size,
                              hipStream_t stream) {
    const float* src = (const float*)d_in[0];
    const float* tgt = (const float*)d_in[1];
    char* ws = (char*)d_ws;
    float* sq    = (float*)ws;
    float* v     = (float*)(ws + 32768);
    float* Fpart = (float*)(ws + 295040);
    unsigned char* img = (unsigned char*)(ws + IMG_OFF);
    float* out = (float*)d_out;

    hipMemsetAsync(ws, 0, 34816, stream);   // sq + v (atomic targets)
    hipLaunchKernelGGL(k_pre, dim3(512), dim3(256), 0, stream, src, tgt, img, sq, v);
    hipLaunchKernelGGL(kmain, dim3(NPAIRS), dim3(256), 0, stream, img, sq, v, Fpart);
    hipLaunchKernelGGL(k4_out, dim3(1), dim3(256), 0, stream, Fpart, out);
}

// Round 9
// 60.982 us; speedup vs baseline: 1.2906x; 1.2906x over previous
//
#include <hip/hip_runtime.h>
#include <hip/hip_bf16.h>

// MMD loss, MI355X. Round 8: revert LDS staging (barrier-drain regression);
// raise per-wave intensity instead: wave tile 128x64, block 256x128 (4 waves),
// 1056 blocks, direct global fragment loads, triangle weights elementwise on
// the 64 diagonal-straddle blocks. int8 Gram, craw fused.
//
// ws layout (NEED = 327680 + 4 MiB):
//   [0,32768)          float sq[8192]     raw sum q^2 per row (integer-exact)
//   [32768,34816)      float v[512]       col sums of q (integer-exact)
//   [295040,299264)    float Fpart[1056]
//   [327680,+4 MiB)    int8 img: 64 panels x 8 kp x 8 groups x 64 lanes x 16B
//     lane chunk = rows g*16+(lane&15), cols kp*64 + (lane>>4)*16 .. +16

typedef int i32x4 __attribute__((ext_vector_type(4)));

#define N_TOT  8192
#define NHALF  4096
#define DIM    512
#define BM     128
#define NBLK   1056      // sum_{I2=0}^{31} (64 - 2*I2)
#define QSCALE 24.0f
#define IMG_OFF 327680ULL

__device__ __forceinline__ int q8(float x) {
    int q = __float2int_rn(x * QSCALE);
    return max(-127, min(127, q));
}

// pre-pass: 512 blocks = (panel p, kp). 128 rows x 64 cols each.
__global__ __launch_bounds__(256) void k_pre(
    const float* __restrict__ src, const float* __restrict__ tgt,
    unsigned char* __restrict__ img,
    float* __restrict__ sq, float* __restrict__ v)
{
    __shared__ __align__(16) signed char qt[BM][80];
    const int b = blockIdx.x;
    const int p = b >> 3, kp = b & 7;
    const int t = threadIdx.x;
    const float* base = ((p < 32) ? src + (size_t)p * BM * DIM
                                  : tgt + (size_t)(p - 32) * BM * DIM) + kp * 64;
    {
        int r = t >> 1, ch = (t & 1) * 32;
        const float* qp = base + (size_t)r * DIM + ch;
        float rsq = 0.f;
        #pragma unroll
        for (int j = 0; j < 8; ++j) {
            float4 x = *(const float4*)(qp + j * 4);
            int q0 = q8(x.x), q1 = q8(x.y), q2 = q8(x.z), q3 = q8(x.w);
            unsigned int w = (q0 & 255) | ((q1 & 255) << 8) | ((q2 & 255) << 16)
                             | ((unsigned)(q3 & 255) << 24);
            *(unsigned int*)&qt[r][ch + j * 4] = w;
            rsq += (float)(q0 * q0 + q1 * q1 + q2 * q2 + q3 * q3);
        }
        rsq += __shfl_xor(rsq, 1);
        if ((t & 1) == 0) atomicAdd(&sq[p * BM + r], rsq);
    }
    __syncthreads();
    #pragma unroll
    for (int h = 0; h < 2; ++h) {
        int ci = t + h * 256;                 // 0..511 = g*64 + lane
        int g = ci >> 6, lane = ci & 63;
        int row = g * 16 + (lane & 15), c0 = (lane >> 4) * 16;
        uint4 w = *(const uint4*)&qt[row][c0];
        *(uint4*)(img + (size_t)p * 65536 + (size_t)kp * 8192
                  + (size_t)g * 1024 + (size_t)lane * 16) = w;
    }
    if (t < 64) {
        float s = 0.f;
        for (int r = 0; r < BM; ++r) s += (float)qt[r][t];
        atomicAdd(&v[kp * 64 + t], s);
    }
}

__global__ __launch_bounds__(256, 2) void kmain(
    const unsigned char* __restrict__ img,
    const float* __restrict__ sq, const float* __restrict__ v,
    float* __restrict__ Fpart)
{
    __shared__ float red[4], redS[4], redV[4];

    // XCD swizzle (1056 = 8*132), then (I2, J) walk: J >= 2*I2
    int b = blockIdx.x;
    int s = (b & 7) * (NBLK / 8) + (b >> 3);
    int I2 = 0, rem = s;
    while (rem >= 64 - 2 * I2) { rem -= 64 - 2 * I2; ++I2; }
    const int J = 2 * I2 + rem;
    const bool straddle = (J >> 1) == I2;

    const int tid  = threadIdx.x;
    const int lane = tid & 63;
    const int wid  = tid >> 6;
    const int wr   = wid >> 1, wc = wid & 1;   // 2x2 waves; wave tile 128x64
    const int lhi  = lane >> 4, llo = lane & 15;

    // A panel = 2*I2 + wr (128 rows); B panel = J, col-half wc
    const char* gA = (const char*)img + (size_t)(2 * I2 + wr) * 65536;
    const char* gB = (const char*)img + (size_t)J * 65536 + (size_t)wc * 4096;
    const int lofs = lane * 16;

    // bandwidth partials (identical deterministic reduction per block)
    float Sp = 0.f;
    #pragma unroll
    for (int i = 0; i < 32; ++i) Sp += sq[tid + i * 256];
    float Vp;
    { float v0 = v[tid], v1 = v[tid + 256]; Vp = v0 * v0 + v1 * v1; }

    i32x4 acc[8][4];
    #pragma unroll
    for (int m = 0; m < 8; ++m)
        #pragma unroll
        for (int n = 0; n < 4; ++n) acc[m][n] = (i32x4){0, 0, 0, 0};

    #pragma unroll
    for (int kp = 0; kp < 8; ++kp) {
        i32x4 aF[8], bF[4];
        #pragma unroll
        for (int m = 0; m < 8; ++m)
            aF[m] = *(const i32x4*)(gA + (size_t)kp * 8192 + m * 1024 + lofs);
        #pragma unroll
        for (int n = 0; n < 4; ++n)
            bF[n] = *(const i32x4*)(gB + (size_t)kp * 8192 + n * 1024 + lofs);
        #pragma unroll
        for (int m = 0; m < 8; ++m)
            #pragma unroll
            for (int n = 0; n < 4; ++n)
                acc[m][n] = __builtin_amdgcn_mfma_i32_16x16x64_i8(
                    aF[m], bF[n], acc[m][n], 0, 0, 0);
    }

    // finish bandwidth (identical in every block)
    #pragma unroll
    for (int off = 32; off > 0; off >>= 1) {
        Sp += __shfl_down(Sp, off);
        Vp += __shfl_down(Vp, off);
    }
    if (lane == 0) { redS[wid] = Sp; redV[wid] = Vp; }
    __syncthreads();
    float S = redS[0] + redS[1] + redS[2] + redS[3];
    float V = redV[0] + redV[1] + redV[2] + redV[3];
    float sumd2 = 2.f * (float)N_TOT * S - 2.f * V;
    float bw = sumd2 / ((float)N_TOT * (float)N_TOT - (float)N_TOT) * 0.25f;
    const float c = 1.4426950408889634f / (16.f * bw);

    // epilogue
    const int rbase = I2 * 256 + wr * 128;     // global row of acc m=0,r'=0
    const int cbase = J * 128 + wc * 64;       // global col of acc n=0,llo=0
    float sqr_[8][4], sqc_[4];
    #pragma unroll
    for (int m = 0; m < 8; ++m)
        #pragma unroll
        for (int r = 0; r < 4; ++r)
            sqr_[m][r] = sq[rbase + m * 16 + lhi * 4 + r];
    #pragma unroll
    for (int n = 0; n < 4; ++n)
        sqc_[n] = sq[cbase + n * 16 + llo];

    float local = 0.f;
    #pragma unroll
    for (int m = 0; m < 8; ++m)
        #pragma unroll
        for (int n = 0; n < 4; ++n)
            #pragma unroll
            for (int r = 0; r < 4; ++r) {
                float d2 = sqr_[m][r] + sqc_[n] - 2.f * (float)acc[m][n][r];
                d2 = fmaxf(d2, 0.f);
                float u = __builtin_amdgcn_exp2f(-d2 * c);
                float u2 = u * u, u4 = u2 * u2, u8 = u4 * u4, u16 = u8 * u8;
                float kv = u + u2 + u4 + u8 + u16;
                if (straddle) {
                    int gi = rbase + m * 16 + lhi * 4 + r;
                    int gj = cbase + n * 16 + llo;
                    kv *= (gj > gi) ? 2.f : ((gj == gi) ? 1.f : 0.f);
                    local += kv;
                } else {
                    local += kv;   // uniform x2 applied below
                }
            }

    float sign = ((I2 < 16) == (J < 32)) ? 1.f : -1.f;
    local *= straddle ? sign : (2.f * sign);

    #pragma unroll
    for (int off = 32; off > 0; off >>= 1) local += __shfl_down(local, off);
    if (lane == 0) red[wid] = local;
    __syncthreads();
    if (tid == 0) Fpart[b] = red[0] + red[1] + red[2] + red[3];
}

__global__ void k4_out(const float* __restrict__ Fpart, float* __restrict__ out) {
    int t = threadIdx.x;
    double s = 0.0;
    for (int i = t; i < NBLK; i += 256) s += (double)Fpart[i];
    #pragma unroll
    for (int off = 32; off > 0; off >>= 1) s += __shfl_down(s, off);
    __shared__ double r[4];
    if ((t & 63) == 0) r[t >> 6] = s;
    __syncthreads();
    if (t == 0) out[0] = (float)((r[0] + r[1] + r[2] + r[3]) / ((double)NHALF * (double)NHALF));
}

extern "C" void kernel_launch(void* const* d_in, const int* in_sizes, int n_in,
                              void* d_out, int out_size, void* d_ws, size_t ws_size,
                              hipStream_t stream) {
    const float* src = (const float*)d_in[0];
    const float* tgt = (const float*)d_in[1];
    char* ws = (char*)d_ws;
    float* sq    = (float*)ws;
    float* v     = (float*)(ws + 32768);
    float* Fpart = (float*)(ws + 295040);
    unsigned char* img = (unsigned char*)(ws + IMG_OFF);
    float* out = (float*)d_out;

    hipMemsetAsync(ws, 0, 34816, stream);   // sq + v (atomic targets)
    hipLaunchKernelGGL(k_pre, dim3(512), dim3(256), 0, stream, src, tgt, img, sq, v);
    hipLaunchKernelGGL(kmain, dim3(NBLK), dim3(256), 0, stream, img, sq, v, Fpart);
    hipLaunchKernelGGL(k4_out, dim3(1), dim3(256), 0, stream, Fpart, out);
}

// Round 10
// 58.307 us; speedup vs baseline: 1.3498x; 1.0459x over previous
//
#include <hip/hip_runtime.h>
#include <hip/hip_bf16.h>

// MMD loss, MI355X. Round 9: occupancy-first. Round-5 structure (int8 Gram,
// 2080 pairs, 64x64 wave tile) with total regs <=128/thread -> 4 waves/SIMD
// (__launch_bounds__(256,4)), zero hoists across the K-loop, separate k3_bw.
//
// ws layout (NEED = 327680 + 4 MiB):
//   [0,32768)          float sq[8192]     raw sum q^2 per row (integer-exact)
//   [32768,34816)      float v[512]       col sums of q (integer-exact)
//   [34816,34820)      float craw
//   [295040,303360)    float Fpart[2080]
//   [327680,+4 MiB)    int8 img: 64 panels x 8 kp x 8 groups x 64 lanes x 16B
//     lane chunk = rows g*16+(lane&15), cols kp*64 + (lane>>4)*16 .. +16

typedef int i32x4 __attribute__((ext_vector_type(4)));

#define N_TOT  8192
#define NHALF  4096
#define DIM    512
#define BM     128
#define TILES  64
#define NPAIRS 2080
#define QSCALE 24.0f
#define IMG_OFF 327680ULL

__device__ __forceinline__ int q8(float x) {
    int q = __float2int_rn(x * QSCALE);
    return max(-127, min(127, q));
}

// pre-pass: 512 blocks = (panel p, kp). 128 rows x 64 cols each.
__global__ __launch_bounds__(256) void k_pre(
    const float* __restrict__ src, const float* __restrict__ tgt,
    unsigned char* __restrict__ img,
    float* __restrict__ sq, float* __restrict__ v)
{
    __shared__ __align__(16) signed char qt[BM][80];
    const int b = blockIdx.x;
    const int p = b >> 3, kp = b & 7;
    const int t = threadIdx.x;
    const float* base = ((p < 32) ? src + (size_t)p * BM * DIM
                                  : tgt + (size_t)(p - 32) * BM * DIM) + kp * 64;
    {
        int r = t >> 1, ch = (t & 1) * 32;
        const float* qp = base + (size_t)r * DIM + ch;
        float rsq = 0.f;
        #pragma unroll
        for (int j = 0; j < 8; ++j) {
            float4 x = *(const float4*)(qp + j * 4);
            int q0 = q8(x.x), q1 = q8(x.y), q2 = q8(x.z), q3 = q8(x.w);
            unsigned int w = (q0 & 255) | ((q1 & 255) << 8) | ((q2 & 255) << 16)
                             | ((unsigned)(q3 & 255) << 24);
            *(unsigned int*)&qt[r][ch + j * 4] = w;
            rsq += (float)(q0 * q0 + q1 * q1 + q2 * q2 + q3 * q3);
        }
        rsq += __shfl_xor(rsq, 1);
        if ((t & 1) == 0) atomicAdd(&sq[p * BM + r], rsq);
    }
    __syncthreads();
    #pragma unroll
    for (int h = 0; h < 2; ++h) {
        int ci = t + h * 256;                 // 0..511 = g*64 + lane
        int g = ci >> 6, lane = ci & 63;
        int row = g * 16 + (lane & 15), c0 = (lane >> 4) * 16;
        uint4 w = *(const uint4*)&qt[row][c0];
        *(uint4*)(img + (size_t)p * 65536 + (size_t)kp * 8192
                  + (size_t)g * 1024 + (size_t)lane * 16) = w;
    }
    if (t < 64) {
        float s = 0.f;
        for (int r = 0; r < BM; ++r) s += (float)qt[r][t];
        atomicAdd(&v[kp * 64 + t], s);
    }
}

// craw = log2e / (16 * bw_raw);  bw_raw = (2n*S - 2||v||^2)/(n^2-n)/4
__global__ void k3_bw(const float* __restrict__ sq, const float* __restrict__ v,
                      float* __restrict__ craw) {
    int t = threadIdx.x;
    double s = 0.0, vv = 0.0;
    for (int i = t; i < N_TOT; i += 256) s += (double)sq[i];
    for (int i = t; i < DIM; i += 256) { double x = (double)v[i]; vv += x * x; }
    #pragma unroll
    for (int off = 32; off > 0; off >>= 1) {
        s  += __shfl_down(s, off);
        vv += __shfl_down(vv, off);
    }
    __shared__ double rs[4], rv[4];
    if ((t & 63) == 0) { rs[t >> 6] = s; rv[t >> 6] = vv; }
    __syncthreads();
    if (t == 0) {
        double S = rs[0] + rs[1] + rs[2] + rs[3];
        double V = rv[0] + rv[1] + rv[2] + rv[3];
        double sumd2 = 2.0 * (double)N_TOT * S - 2.0 * V;
        double bw = sumd2 / ((double)N_TOT * N_TOT - (double)N_TOT) / 4.0;
        *craw = (float)(1.4426950408889634 / (16.0 * bw));
    }
}

__global__ __launch_bounds__(256, 4) void kmain(
    const unsigned char* __restrict__ img,
    const float* __restrict__ sq, const float* __restrict__ craw_p,
    float* __restrict__ Fpart)
{
    __shared__ float red[4];

    // XCD swizzle (2080 = 8*260), then 4x4-supertile triangle walk
    int b = blockIdx.x;
    int s = (b & 7) * (NPAIRS / 8) + (b >> 3);
    int SI = 0, rem = s;
    while (rem >= 10 + 16 * (15 - SI)) { rem -= 10 + 16 * (15 - SI); ++SI; }
    int I, J;
    if (rem < 10) {
        int di = 0;
        while (rem >= 4 - di) { rem -= 4 - di; ++di; }
        I = SI * 4 + di; J = SI * 4 + di + rem;
    } else {
        rem -= 10;
        int SJ = SI + 1 + (rem >> 4);
        I = SI * 4 + ((rem >> 2) & 3);
        J = SJ * 4 + (rem & 3);
    }

    const int tid  = threadIdx.x;
    const int lane = tid & 63;
    const int wid  = tid >> 6;
    const int wr   = wid >> 1, wc = wid & 1;
    const int lhi  = lane >> 4, llo = lane & 15;

    const char* gA = (const char*)img + (size_t)I * 65536;
    const char* gB = (const char*)img + (size_t)J * 65536;
    const int vA = wr * 4096 + lane * 16;
    const int vB = wc * 4096 + lane * 16;

    i32x4 acc[4][4];
    #pragma unroll
    for (int m = 0; m < 4; ++m)
        #pragma unroll
        for (int n = 0; n < 4; ++n) acc[m][n] = (i32x4){0, 0, 0, 0};

    // K-loop: plain unrolled loads + MFMAs; latency hidden by 4 waves/SIMD
    #pragma unroll
    for (int kp = 0; kp < 8; ++kp) {
        i32x4 aF[4], bF[4];
        #pragma unroll
        for (int m = 0; m < 4; ++m) {
            aF[m] = *(const i32x4*)(gA + (size_t)kp * 8192 + m * 1024 + vA);
            bF[m] = *(const i32x4*)(gB + (size_t)kp * 8192 + m * 1024 + vB);
        }
        #pragma unroll
        for (int m = 0; m < 4; ++m)
            #pragma unroll
            for (int n = 0; n < 4; ++n)
                acc[m][n] = __builtin_amdgcn_mfma_i32_16x16x64_i8(
                    aF[m], bF[n], acc[m][n], 0, 0, 0);
    }

    // epilogue inputs loaded AFTER the K-loop (L2-hot; keeps K-loop regs lean)
    const float c = *craw_p;
    const int rI = I * BM, rJ = J * BM;
    float sqc_[4];
    #pragma unroll
    for (int n = 0; n < 4; ++n)
        sqc_[n] = sq[rJ + wc * 64 + n * 16 + llo];

    float local = 0.f;
    #pragma unroll
    for (int m = 0; m < 4; ++m) {
        float sqr_[4];
        #pragma unroll
        for (int r = 0; r < 4; ++r)
            sqr_[r] = sq[rI + wr * 64 + m * 16 + lhi * 4 + r];
        #pragma unroll
        for (int n = 0; n < 4; ++n)
            #pragma unroll
            for (int r = 0; r < 4; ++r) {
                float d2 = sqr_[r] + sqc_[n] - 2.f * (float)acc[m][n][r];
                d2 = fmaxf(d2, 0.f);
                float u = __builtin_amdgcn_exp2f(-d2 * c);
                float u2 = u * u, u4 = u2 * u2, u8 = u4 * u4, u16 = u8 * u8;
                local += u + u2 + u4 + u8 + u16;
            }
    }

    float wgt = ((I < 32) == (J < 32)) ? 1.f : -1.f;
    if (I != J) wgt *= 2.f;
    local *= wgt;

    #pragma unroll
    for (int off = 32; off > 0; off >>= 1) local += __shfl_down(local, off);
    if (lane == 0) red[wid] = local;
    __syncthreads();
    if (tid == 0) Fpart[b] = red[0] + red[1] + red[2] + red[3];
}

__global__ void k4_out(const float* __restrict__ Fpart, float* __restrict__ out) {
    int t = threadIdx.x;
    double s = 0.0;
    for (int i = t; i < NPAIRS; i += 256) s += (double)Fpart[i];
    #pragma unroll
    for (int off = 32; off > 0; off >>= 1) s += __shfl_down(s, off);
    __shared__ double r[4];
    if ((t & 63) == 0) r[t >> 6] = s;
    __syncthreads();
    if (t == 0) out[0] = (float)((r[0] + r[1] + r[2] + r[3]) / ((double)NHALF * (double)NHALF));
}

extern "C" void kernel_launch(void* const* d_in, const int* in_sizes, int n_in,
                              void* d_out, int out_size, void* d_ws, size_t ws_size,
                              hipStream_t stream) {
    const float* src = (const float*)d_in[0];
    const float* tgt = (const float*)d_in[1];
    char* ws = (char*)d_ws;
    float* sq    = (float*)ws;
    float* v     = (float*)(ws + 32768);
    float* craw  = (float*)(ws + 34816);
    float* Fpart = (float*)(ws + 295040);
    unsigned char* img = (unsigned char*)(ws + IMG_OFF);
    float* out = (float*)d_out;

    hipMemsetAsync(ws, 0, 34816, stream);   // sq + v (atomic targets)
    hipLaunchKernelGGL(k_pre, dim3(512), dim3(256), 0, stream, src, tgt, img, sq, v);
    hipLaunchKernelGGL(k3_bw, dim3(1), dim3(256), 0, stream, sq, v, craw);
    hipLaunchKernelGGL(kmain, dim3(NPAIRS), dim3(256), 0, stream, img, sq, craw, Fpart);
    hipLaunchKernelGGL(k4_out, dim3(1), dim3(256), 0, stream, Fpart, out);
}